// Round 11
// baseline (142.721 us; speedup 1.0000x reference)
//
#include <hip/hip_runtime.h>
#include <hip/hip_bf16.h>

// Problem constants (B=64, N=1024, D=128, K=6)
#define CB 64
#define CN 1024
#define CD 128
#define CK 6

typedef __attribute__((ext_vector_type(8))) short short8;
typedef __attribute__((ext_vector_type(4))) float floatx4;

__device__ __forceinline__ unsigned short f2bf(float f) {
    union { float f; unsigned u; } c; c.f = f;
    unsigned u = c.u;
    u += 0x7FFFu + ((u >> 16) & 1u);
    return (unsigned short)(u >> 16);
}
__device__ __forceinline__ float bf2f(unsigned short u) {
    union { unsigned u; float f; } c; c.u = ((unsigned)u) << 16; return c.f;
}
// element dd (0..7) of a uint4 holding 8 bf16
__device__ __forceinline__ float bfe(const uint4& g, int dd) {
    unsigned w = (&g.x)[dd >> 1];
    unsigned short h = (dd & 1) ? (unsigned short)(w >> 16)
                                : (unsigned short)(w & 0xFFFFu);
    return bf2f(h);
}

// ws layout (bytes) — ws is 256 MiB
#define WS_G      0          // [1024][6][128] bf16 = 1.5 MB (G16[m][k][d])
#define WS_IDS    3932160    // [64][1024] u16 = 128 KB
#define WS_STARTS 4063232    // [64][257] i32 = 64.25 KB
#define WS_PART   4129024    // [1024][128] f32 = 512 KB

struct SortSM { float2 pts[CN]; int cnt[256]; int base[256]; };
struct GSM    { unsigned short As[128 * 40]; unsigned short Bs[128 * 40]; };
union GridSM  { SortSM s; GSM g; };

// ---------------------------------------------------------------------------
// k_gridg: blocks 0..63 = per-batch counting sort; blocks 64..111 = G
// precompute (G_k = F2 @ Wnb_k^T, bf16 MFMA), stored bf16. Proven r10.
// ---------------------------------------------------------------------------
__global__ void __launch_bounds__(256) k_gridg(
    const float* __restrict__ loc,
    const float* __restrict__ W2d,
    const float* __restrict__ b2d,
    const float* __restrict__ Wnb,
    unsigned short* __restrict__ ids,
    int* __restrict__ starts,
    unsigned short* __restrict__ G16)
{
    __shared__ GridSM sm;
    int t = threadIdx.x;

    if (blockIdx.x < 64) {
        int b = blockIdx.x;
        const float2* lb = (const float2*)loc + b * CN;
#pragma unroll
        for (int r = 0; r < 4; ++r) sm.s.pts[t + r * 256] = lb[t + r * 256];
        sm.s.cnt[t] = 0;
        __syncthreads();
        int mycell[4];
#pragma unroll
        for (int r = 0; r < 4; ++r) {
            float2 p = sm.s.pts[t * 4 + r];
            int cx = (int)(p.x * 16.0f); cx = cx > 15 ? 15 : cx;
            int cy = (int)(p.y * 16.0f); cy = cy > 15 ? 15 : cy;
            mycell[r] = (cy << 4) + cx;
            atomicAdd(&sm.s.cnt[mycell[r]], 1);
        }
        __syncthreads();
        for (int off = 1; off < 256; off <<= 1) {
            int u = (t >= off) ? sm.s.cnt[t - off] : 0;
            __syncthreads();
            sm.s.cnt[t] += u;
            __syncthreads();
        }
        int excl = (t == 0) ? 0 : sm.s.cnt[t - 1];
        sm.s.base[t] = excl;
        starts[b * 257 + t] = excl;
        if (t == 255) starts[b * 257 + 256] = sm.s.cnt[255];
        __syncthreads();
#pragma unroll
        for (int r = 0; r < 4; ++r) {
            int pos = atomicAdd(&sm.s.base[mycell[r]], 1);
            ids[b * CN + pos] = (unsigned short)(t * 4 + r);
        }
        return;
    }

    int gb = blockIdx.x - 64;          // 0..47
    int k = gb % 6;
    int tile = gb / 6;                 // 0..7
    int n0 = tile << 7;                // 128 rows per tile

    int wave = t >> 6, lane = t & 63;
    int koff = (lane >> 4) * 8;
    int mrow = lane & 15;

    int e2 = t & 15, rg = t >> 4;
    float2 pl[8];
#pragma unroll
    for (int rr = 0; rr < 8; ++rr)
        pl[rr] = ((const float2*)loc)[n0 + rg + rr * 16];

    int bd = t >> 1, bhalf = t & 1;

    floatx4 acc[2][8];
#pragma unroll
    for (int i = 0; i < 2; ++i)
#pragma unroll
        for (int j = 0; j < 8; ++j) acc[i][j] = (floatx4){0.f, 0.f, 0.f, 0.f};

#pragma unroll
    for (int c = 0; c < 4; ++c) {
        __syncthreads();
        {
            int e0 = c * 32 + e2 * 2;
            float wx0 = W2d[e0 * 2],     wy0 = W2d[e0 * 2 + 1], bz0 = b2d[e0];
            float wx1 = W2d[e0 * 2 + 2], wy1 = W2d[e0 * 2 + 3], bz1 = b2d[e0 + 1];
#pragma unroll
            for (int rr = 0; rr < 8; ++rr) {
                float2 p = pl[rr];
                float v0 = fmaf(p.x, wx0, fmaf(p.y, wy0, bz0));
                float v1 = fmaf(p.x, wx1, fmaf(p.y, wy1, bz1));
                unsigned pack = (unsigned)f2bf(v0) | ((unsigned)f2bf(v1) << 16);
                *(unsigned*)&sm.g.As[(rg + rr * 16) * 40 + e2 * 2] = pack;
            }
        }
        {
            const float* src = Wnb + bd * 768 + k * 128 + c * 32 + bhalf * 16;
            float4 f0 = *(const float4*)(src);
            float4 f1 = *(const float4*)(src + 4);
            float4 f2v = *(const float4*)(src + 8);
            float4 f3 = *(const float4*)(src + 12);
            uint4 o0, o1;
            o0.x = (unsigned)f2bf(f0.x) | ((unsigned)f2bf(f0.y) << 16);
            o0.y = (unsigned)f2bf(f0.z) | ((unsigned)f2bf(f0.w) << 16);
            o0.z = (unsigned)f2bf(f1.x) | ((unsigned)f2bf(f1.y) << 16);
            o0.w = (unsigned)f2bf(f1.z) | ((unsigned)f2bf(f1.w) << 16);
            o1.x = (unsigned)f2bf(f2v.x) | ((unsigned)f2bf(f2v.y) << 16);
            o1.y = (unsigned)f2bf(f2v.z) | ((unsigned)f2bf(f2v.w) << 16);
            o1.z = (unsigned)f2bf(f3.x) | ((unsigned)f2bf(f3.y) << 16);
            o1.w = (unsigned)f2bf(f3.z) | ((unsigned)f2bf(f3.w) << 16);
            *(uint4*)&sm.g.Bs[bd * 40 + bhalf * 16] = o0;
            *(uint4*)&sm.g.Bs[bd * 40 + bhalf * 16 + 8] = o1;
        }
        __syncthreads();
        short8 af[2];
#pragma unroll
        for (int i = 0; i < 2; ++i)
            af[i] = *(const short8*)&sm.g.As[(wave * 32 + i * 16 + mrow) * 40 + koff];
#pragma unroll
        for (int j = 0; j < 8; ++j) {
            short8 bfr = *(const short8*)&sm.g.Bs[(j * 16 + mrow) * 40 + koff];
#pragma unroll
            for (int i = 0; i < 2; ++i)
                acc[i][j] = __builtin_amdgcn_mfma_f32_16x16x32_bf16(
                    af[i], bfr, acc[i][j], 0, 0, 0);
        }
    }

    int lq = lane >> 4, lc = lane & 15;
#pragma unroll
    for (int j = 0; j < 8; ++j) {
        int d = j * 16 + lc;
#pragma unroll
        for (int i = 0; i < 2; ++i) {
#pragma unroll
            for (int r = 0; r < 4; ++r) {
                int row = wave * 32 + i * 16 + lq * 4 + r;
                G16[(n0 + row) * 768 + k * 128 + d] = f2bf(acc[i][j][r]);
            }
        }
    }
}

// ---------------------------------------------------------------------------
// k_knngather: knn (proven original) FUSED with the r10 bf16 gather. Same
// 1024-block geometry as both parents (16 blocks/batch x 64 queries). The
// knn phase writes each query's 6 neighbor indices to LDS (nbs) instead of
// global; after one barrier the gather phase consumes them directly. Removes
// one kernel launch + the cross-kernel barrier (gather of fast blocks now
// overlaps knn of slow blocks) + the 768 KB nbrs round-trip. All arithmetic
// bit-identical to r10.
// ---------------------------------------------------------------------------
__global__ void __launch_bounds__(256) k_knngather(
    const float* __restrict__ loc,
    const float* __restrict__ dl,
    const unsigned short* __restrict__ ids,
    const int* __restrict__ starts,
    const unsigned short* __restrict__ G16,
    const float* __restrict__ W3d,
    const float* __restrict__ b3d,
    const float* __restrict__ bnb,
    float* __restrict__ outh,          // [64][1025][128]
    float* __restrict__ partials)      // [1024][128]
{
    __shared__ float2 xy_tmp[CN];              // 8 KB
    __shared__ float2 xy_s[CN];                // 8 KB
    __shared__ unsigned short ids_s[CN];       // 2 KB
    __shared__ int st_s[257];                  // 1 KB
    __shared__ unsigned short nbs[64 * CK];    // 768 B
    __shared__ float psum[4][CD];              // 2 KB
    int t = threadIdx.x;
    int b = blockIdx.x >> 4;
    int qbase = (blockIdx.x & 15) << 6;
    const float2* lb = (const float2*)loc + b * CN;
#pragma unroll
    for (int r = 0; r < 4; ++r) {
        int p = t + r * 256;
        xy_tmp[p] = lb[p];
        ids_s[p] = ids[b * CN + p];
    }
    st_s[t] = starts[b * 257 + t];
    if (t == 0) st_s[256] = starts[b * 257 + 256];
    __syncthreads();
#pragma unroll
    for (int r = 0; r < 4; ++r) {
        int p = t + r * 256;
        xy_s[p] = xy_tmp[ids_s[p]];
    }
    __syncthreads();

    int qp = qbase + (t >> 2);
    int pi = t & 3;
    float2 qxy = xy_s[qp];
    float xq = qxy.x, yq = qxy.y;
    int cx = (int)(xq * 16.0f); cx = cx > 15 ? 15 : cx;
    int cy = (int)(yq * 16.0f); cy = cy > 15 ? 15 : cy;
    float dk[CK]; int ik[CK];
#pragma unroll
    for (int s = 0; s < CK; ++s) { dk[s] = 1e30f; ik[s] = 0x7FFFFFFF; }
    float dk5sq = __builtin_inff();
    const float h = 0.0625f;

#define KNN_CAND(P)                                                        \
    {                                                                      \
        float2 v = xy_s[P];                                                \
        float dx = __fsub_rn(v.x, xq);                                     \
        float dy = __fsub_rn(v.y, yq);                                     \
        float d2 = __fadd_rn(__fmul_rn(dx, dx), __fmul_rn(dy, dy));        \
        if (d2 < dk5sq) {                                                  \
            float ds = __fsqrt_rn(d2);                                     \
            int j = ids_s[P];                                              \
            if (ds < dk[CK - 1] || (ds == dk[CK - 1] && j < ik[CK - 1])) { \
                float dc = ds; int jc = j;                                 \
                _Pragma("unroll")                                          \
                for (int s = 0; s < CK; ++s) {                             \
                    bool sw = (dc < dk[s]) || (dc == dk[s] && jc < ik[s]); \
                    float od = dk[s]; int oi = ik[s];                      \
                    dk[s] = sw ? dc : od; ik[s] = sw ? jc : oi;            \
                    dc = sw ? od : dc;    jc = sw ? oi : jc;               \
                }                                                          \
                if (ik[CK - 1] != 0x7FFFFFFF)                              \
                    dk5sq = __fmul_rn(dk[CK - 1], dk[CK - 1]) * 1.000001f; \
            }                                                              \
        }                                                                  \
    }

    // ---- fast path: 3x3 neighborhood = 3 contiguous sorted ranges
    {
        int yl = cy > 0 ? cy - 1 : 0, yh = cy < 15 ? cy + 1 : 15;
        int xl = cx > 0 ? cx - 1 : 0, xh = cx < 15 ? cx + 1 : 15;
        for (int yy = yl; yy <= yh; ++yy) {
            int p  = st_s[(yy << 4) + xl] + pi;
            int pe = st_s[(yy << 4) + xh + 1];
            for (; p < pe; p += 4) KNN_CAND(p)
        }
    }
    // certified r=1 stop (per-thread, conservative)
    bool done;
    {
        int x0 = cx - 1, x1 = cx + 1, y0 = cy - 1, y1 = cy + 1;
        done = (x0 <= 0 && y0 <= 0 && x1 >= 15 && y1 >= 15);
        float mL = x0 > 0  ? __fsub_rn(xq, (float)x0 * h)       : 1e30f;
        float mR = x1 < 15 ? __fsub_rn((float)(x1 + 1) * h, xq) : 1e30f;
        float mB = y0 > 0  ? __fsub_rn(yq, (float)y0 * h)       : 1e30f;
        float mT = y1 < 15 ? __fsub_rn((float)(y1 + 1) * h, yq) : 1e30f;
        float bound = fminf(fminf(mL, mR), fminf(mB, mT)) * 0.999999f;
        done = done || (ik[CK - 1] != 0x7FFFFFFF && dk[CK - 1] < bound);
    }
    // ---- rare fallback: general ring expansion from r=2 (same partition)
    if (!done) {
        for (int r = 2; r < 16; ++r) {
            int x0 = cx - r, x1 = cx + r, y0 = cy - r, y1 = cy + r;
            int yl = y0 < 0 ? 0 : y0, yh = y1 > 15 ? 15 : y1;
            int xl = x0 < 0 ? 0 : x0, xh = x1 > 15 ? 15 : x1;
            for (int yy = yl; yy <= yh; ++yy) {
                bool ey = (yy == y0) || (yy == y1);
                if (ey) {
                    int p  = st_s[(yy << 4) + xl] + pi;
                    int pe = st_s[(yy << 4) + xh + 1];
                    for (; p < pe; p += 4) KNN_CAND(p)
                } else {
                    if (x0 >= 0) {
                        int p  = st_s[(yy << 4) + x0] + pi;
                        int pe = st_s[(yy << 4) + x0 + 1];
                        for (; p < pe; p += 4) KNN_CAND(p)
                    }
                    if (x1 <= 15) {
                        int p  = st_s[(yy << 4) + x1] + pi;
                        int pe = st_s[(yy << 4) + x1 + 1];
                        for (; p < pe; p += 4) KNN_CAND(p)
                    }
                }
            }
            if (x0 <= 0 && y0 <= 0 && x1 >= 15 && y1 >= 15) break;
            float mL = x0 > 0  ? __fsub_rn(xq, (float)x0 * h)       : 1e30f;
            float mR = x1 < 15 ? __fsub_rn((float)(x1 + 1) * h, xq) : 1e30f;
            float mB = y0 > 0  ? __fsub_rn(yq, (float)y0 * h)       : 1e30f;
            float mT = y1 < 15 ? __fsub_rn((float)(y1 + 1) * h, yq) : 1e30f;
            float bound = fminf(fminf(mL, mR), fminf(mB, mT)) * 0.999999f;
            if (ik[CK - 1] != 0x7FFFFFFF && dk[CK - 1] < bound) break;
        }
    }
#undef KNN_CAND

#define KNN_MERGE(MASK)                                                     \
    {                                                                       \
        float od[CK]; int oi[CK];                                           \
        _Pragma("unroll")                                                   \
        for (int s = 0; s < CK; ++s) {                                      \
            od[s] = __shfl_xor(dk[s], MASK);                                \
            oi[s] = __shfl_xor(ik[s], MASK);                                \
        }                                                                   \
        _Pragma("unroll")                                                   \
        for (int e = 0; e < CK; ++e) {                                      \
            float dc = od[e]; int jc = oi[e];                               \
            if ((dc < dk[CK - 1]) || (dc == dk[CK - 1] && jc < ik[CK - 1])) { \
                _Pragma("unroll")                                           \
                for (int s = 0; s < CK; ++s) {                              \
                    bool sw = (dc < dk[s]) || (dc == dk[s] && jc < ik[s]);  \
                    float td = dk[s]; int ti = ik[s];                       \
                    dk[s] = sw ? dc : td; ik[s] = sw ? jc : ti;             \
                    dc = sw ? td : dc;    jc = sw ? ti : jc;                \
                }                                                           \
            }                                                               \
        }                                                                   \
    }
    KNN_MERGE(1)
    KNN_MERGE(2)
#undef KNN_MERGE

    // neighbor lists -> LDS, indexed by query slot (t>>2)
    if (pi == 0) {
        unsigned short* o = nbs + (t >> 2) * CK;
#pragma unroll
        for (int s = 0; s < CK; ++s) o[s] = (unsigned short)ik[s];
    }
    __syncthreads();

    // ================= gather phase (r10 bf16, bit-identical) =============
    int d8 = t & 15, rg = t >> 4;             // 16 d-groups x 16 row-groups
    int d0 = d8 * 8;
    float w0[8], w1[8], w2[8], bias[8];
#pragma unroll
    for (int dd = 0; dd < 8; ++dd) {
        int d = d0 + dd;
        w0[dd] = W3d[d * 3];
        w1[dd] = W3d[d * 3 + 1];
        w2[dd] = W3d[d * 3 + 2];
        bias[dd] = b3d[d] + bnb[d];
    }
    float csum[8];
#pragma unroll
    for (int dd = 0; dd < 8; ++dd) csum[dd] = 0.f;

#pragma unroll
    for (int rr = 0; rr < 2; ++rr) {
        int r0 = rr * 32 + rg;               // slots rg, 32+rg
        int r1 = r0 + 16;                    // slots 16+rg, 48+rg
        int n0s = ids_s[qbase + r0], n1s = ids_s[qbase + r1];
        int gr0 = (b << 10) + n0s, gr1 = (b << 10) + n1s;
        const unsigned short* nA = nbs + r0 * CK;
        const unsigned short* nB = nbs + r1 * CK;
        // ---- issue all 12 bf16x8 gathers + 4 small loads, named ----
        uint4 ga0 = *(const uint4*)(G16 + nA[0] * 768 + 0 * 128 + d0);
        uint4 ga1 = *(const uint4*)(G16 + nA[1] * 768 + 1 * 128 + d0);
        uint4 ga2 = *(const uint4*)(G16 + nA[2] * 768 + 2 * 128 + d0);
        uint4 ga3 = *(const uint4*)(G16 + nA[3] * 768 + 3 * 128 + d0);
        uint4 ga4 = *(const uint4*)(G16 + nA[4] * 768 + 4 * 128 + d0);
        uint4 ga5 = *(const uint4*)(G16 + nA[5] * 768 + 5 * 128 + d0);
        uint4 gb0 = *(const uint4*)(G16 + nB[0] * 768 + 0 * 128 + d0);
        uint4 gb1 = *(const uint4*)(G16 + nB[1] * 768 + 1 * 128 + d0);
        uint4 gb2 = *(const uint4*)(G16 + nB[2] * 768 + 2 * 128 + d0);
        uint4 gb3 = *(const uint4*)(G16 + nB[3] * 768 + 3 * 128 + d0);
        uint4 gb4 = *(const uint4*)(G16 + nB[4] * 768 + 4 * 128 + d0);
        uint4 gb5 = *(const uint4*)(G16 + nB[5] * 768 + 5 * 128 + d0);
        float2 lA = ((const float2*)loc)[gr0];
        float2 lB = ((const float2*)loc)[gr1];
        float dA = dl[gr0];
        float dB = dl[gr1];
        // ---- consume row 0 (k-ascending sum order preserved) ----
        {
            float o[8];
#pragma unroll
            for (int dd = 0; dd < 8; ++dd) {
                float a = ((((bfe(ga0, dd) + bfe(ga1, dd)) + bfe(ga2, dd))
                           + bfe(ga3, dd)) + bfe(ga4, dd)) + bfe(ga5, dd);
                float v = a + bias[dd] + lA.x * w0[dd] + lA.y * w1[dd]
                        + dA * w2[dd];
                o[dd] = v >= 0.f ? v : 0.01f * v;
                csum[dd] += o[dd];
            }
            float* ob = outh + ((long)b * 1025 + n0s + 1) * 128 + d0;
            float4 s0, s1;
            s0.x = o[0]; s0.y = o[1]; s0.z = o[2]; s0.w = o[3];
            s1.x = o[4]; s1.y = o[5]; s1.z = o[6]; s1.w = o[7];
            *(float4*)(ob) = s0;
            *(float4*)(ob + 4) = s1;
        }
        // ---- consume row 1 ----
        {
            float o[8];
#pragma unroll
            for (int dd = 0; dd < 8; ++dd) {
                float a = ((((bfe(gb0, dd) + bfe(gb1, dd)) + bfe(gb2, dd))
                           + bfe(gb3, dd)) + bfe(gb4, dd)) + bfe(gb5, dd);
                float v = a + bias[dd] + lB.x * w0[dd] + lB.y * w1[dd]
                        + dB * w2[dd];
                o[dd] = v >= 0.f ? v : 0.01f * v;
                csum[dd] += o[dd];
            }
            float* ob = outh + ((long)b * 1025 + n1s + 1) * 128 + d0;
            float4 s0, s1;
            s0.x = o[0]; s0.y = o[1]; s0.z = o[2]; s0.w = o[3];
            s1.x = o[4]; s1.y = o[5]; s1.z = o[6]; s1.w = o[7];
            *(float4*)(ob) = s0;
            *(float4*)(ob + 4) = s1;
        }
    }

    // within wave: lanes t, t+16, t+32, t+48 share d8 (4 row-groups)
#pragma unroll
    for (int dd = 0; dd < 8; ++dd) {
        csum[dd] += __shfl_xor(csum[dd], 16);
        csum[dd] += __shfl_xor(csum[dd], 32);
    }
    int wave = t >> 6, lane = t & 63;
    if (lane < 16) {
#pragma unroll
        for (int dd = 0; dd < 8; ++dd) psum[wave][d0 + dd] = csum[dd];
    }
    __syncthreads();
    if (t < CD)
        partials[((int)blockIdx.x << 7) + t] =
            psum[0][t] + psum[1][t] + psum[2][t] + psum[3][t];
}

// ---------------------------------------------------------------------------
// k_fin: reduce 16 block-partials/batch + depot row + mean/1025.
// ---------------------------------------------------------------------------
__global__ void k_fin(const float* __restrict__ depot,
                      const float* __restrict__ Wdep,
                      const float* __restrict__ bdep,
                      const float* __restrict__ partials,
                      float* __restrict__ out) {
    int idx = blockIdx.x * 256 + threadIdx.x;   // 64*128
    int b = idx >> 7, d = idx & 127;
    float acc = 0.f;
#pragma unroll
    for (int g = 0; g < 16; ++g) acc += partials[(b * 16 + g) * 128 + d];
    float dv = depot[b * 2] * Wdep[d * 2] + depot[b * 2 + 1] * Wdep[d * 2 + 1] + bdep[d];
    float lr = dv >= 0.f ? dv : 0.01f * dv;
    out[(long)b * 1025 * 128 + d] = lr;
    out[(long)CB * 1025 * 128 + idx] = (acc + lr) * (1.0f / 1025.0f);
}

extern "C" void kernel_launch(void* const* d_in, const int* in_sizes, int n_in,
                              void* d_out, int out_size, void* d_ws, size_t ws_size,
                              hipStream_t stream) {
    const float* loc      = (const float*)d_in[0];
    const float* deadline = (const float*)d_in[1];
    const float* depot    = (const float*)d_in[2];
    const float* W3d      = (const float*)d_in[3];
    const float* b3d      = (const float*)d_in[4];
    const float* W2d      = (const float*)d_in[5];
    const float* b2d      = (const float*)d_in[6];
    const float* Wnb      = (const float*)d_in[7];
    const float* bnb      = (const float*)d_in[8];
    const float* Wdep     = (const float*)d_in[9];
    const float* bdep     = (const float*)d_in[10];
    float* out = (float*)d_out;

    char* ws = (char*)d_ws;
    unsigned short* G16   = (unsigned short*)(ws + WS_G);
    unsigned short* ids   = (unsigned short*)(ws + WS_IDS);
    int* starts           = (int*)(ws + WS_STARTS);
    float* partials       = (float*)(ws + WS_PART);

    k_gridg<<<112, 256, 0, stream>>>(loc, W2d, b2d, Wnb, ids, starts, G16);
    k_knngather<<<1024, 256, 0, stream>>>(loc, deadline, ids, starts, G16,
                                          W3d, b3d, bnb, out, partials);
    k_fin<<<32, 256, 0, stream>>>(depot, Wdep, bdep, partials, out);
}

// Round 12
// 130.764 us; speedup vs baseline: 1.0914x; 1.0914x over previous
//
#include <hip/hip_runtime.h>
#include <hip/hip_bf16.h>

// Problem constants (B=64, N=1024, D=128, K=6)
#define CB 64
#define CN 1024
#define CD 128
#define CK 6

typedef __attribute__((ext_vector_type(8))) short short8;
typedef __attribute__((ext_vector_type(4))) float floatx4;

__device__ __forceinline__ unsigned short f2bf(float f) {
    union { float f; unsigned u; } c; c.f = f;
    unsigned u = c.u;
    u += 0x7FFFu + ((u >> 16) & 1u);
    return (unsigned short)(u >> 16);
}
__device__ __forceinline__ float bf2f(unsigned short u) {
    union { unsigned u; float f; } c; c.u = ((unsigned)u) << 16; return c.f;
}
// element dd (0..7) of a uint4 holding 8 bf16
__device__ __forceinline__ float bfe(const uint4& g, int dd) {
    unsigned w = (&g.x)[dd >> 1];
    unsigned short h = (dd & 1) ? (unsigned short)(w >> 16)
                                : (unsigned short)(w & 0xFFFFu);
    return bf2f(h);
}

// ws layout (bytes) — ws is 256 MiB
#define WS_G      0          // [1024][6][128] bf16 = 1.5 MB (G16[m][k][d])
#define WS_NBRS   3145728    // [65536][6] u16 = 768 KB
#define WS_IDS    3932160    // [64][1024] u16 = 128 KB
#define WS_STARTS 4063232    // [64][257] i32 = 64.25 KB
#define WS_PART   4129024    // [1024][128] f32 = 512 KB

struct SortSM { float2 pts[CN]; int cnt[256]; int base[256]; };
struct GSM    { unsigned short As[128 * 40]; unsigned short Bs[128 * 40]; };
union GridSM  { SortSM s; GSM g; };

// ---------------------------------------------------------------------------
// k_gridg: blocks 0..63 = per-batch counting sort; blocks 64..111 = G
// precompute (G_k = F2 @ Wnb_k^T, bf16 MFMA), stored bf16. Proven r10.
// ---------------------------------------------------------------------------
__global__ void __launch_bounds__(256) k_gridg(
    const float* __restrict__ loc,
    const float* __restrict__ W2d,
    const float* __restrict__ b2d,
    const float* __restrict__ Wnb,
    unsigned short* __restrict__ ids,
    int* __restrict__ starts,
    unsigned short* __restrict__ G16)
{
    __shared__ GridSM sm;
    int t = threadIdx.x;

    if (blockIdx.x < 64) {
        int b = blockIdx.x;
        const float2* lb = (const float2*)loc + b * CN;
#pragma unroll
        for (int r = 0; r < 4; ++r) sm.s.pts[t + r * 256] = lb[t + r * 256];
        sm.s.cnt[t] = 0;
        __syncthreads();
        int mycell[4];
#pragma unroll
        for (int r = 0; r < 4; ++r) {
            float2 p = sm.s.pts[t * 4 + r];
            int cx = (int)(p.x * 16.0f); cx = cx > 15 ? 15 : cx;
            int cy = (int)(p.y * 16.0f); cy = cy > 15 ? 15 : cy;
            mycell[r] = (cy << 4) + cx;
            atomicAdd(&sm.s.cnt[mycell[r]], 1);
        }
        __syncthreads();
        for (int off = 1; off < 256; off <<= 1) {
            int u = (t >= off) ? sm.s.cnt[t - off] : 0;
            __syncthreads();
            sm.s.cnt[t] += u;
            __syncthreads();
        }
        int excl = (t == 0) ? 0 : sm.s.cnt[t - 1];
        sm.s.base[t] = excl;
        starts[b * 257 + t] = excl;
        if (t == 255) starts[b * 257 + 256] = sm.s.cnt[255];
        __syncthreads();
#pragma unroll
        for (int r = 0; r < 4; ++r) {
            int pos = atomicAdd(&sm.s.base[mycell[r]], 1);
            ids[b * CN + pos] = (unsigned short)(t * 4 + r);
        }
        return;
    }

    int gb = blockIdx.x - 64;          // 0..47
    int k = gb % 6;
    int tile = gb / 6;                 // 0..7
    int n0 = tile << 7;                // 128 rows per tile

    int wave = t >> 6, lane = t & 63;
    int koff = (lane >> 4) * 8;
    int mrow = lane & 15;

    int e2 = t & 15, rg = t >> 4;
    float2 pl[8];
#pragma unroll
    for (int rr = 0; rr < 8; ++rr)
        pl[rr] = ((const float2*)loc)[n0 + rg + rr * 16];

    int bd = t >> 1, bhalf = t & 1;

    floatx4 acc[2][8];
#pragma unroll
    for (int i = 0; i < 2; ++i)
#pragma unroll
        for (int j = 0; j < 8; ++j) acc[i][j] = (floatx4){0.f, 0.f, 0.f, 0.f};

#pragma unroll
    for (int c = 0; c < 4; ++c) {
        __syncthreads();
        {
            int e0 = c * 32 + e2 * 2;
            float wx0 = W2d[e0 * 2],     wy0 = W2d[e0 * 2 + 1], bz0 = b2d[e0];
            float wx1 = W2d[e0 * 2 + 2], wy1 = W2d[e0 * 2 + 3], bz1 = b2d[e0 + 1];
#pragma unroll
            for (int rr = 0; rr < 8; ++rr) {
                float2 p = pl[rr];
                float v0 = fmaf(p.x, wx0, fmaf(p.y, wy0, bz0));
                float v1 = fmaf(p.x, wx1, fmaf(p.y, wy1, bz1));
                unsigned pack = (unsigned)f2bf(v0) | ((unsigned)f2bf(v1) << 16);
                *(unsigned*)&sm.g.As[(rg + rr * 16) * 40 + e2 * 2] = pack;
            }
        }
        {
            const float* src = Wnb + bd * 768 + k * 128 + c * 32 + bhalf * 16;
            float4 f0 = *(const float4*)(src);
            float4 f1 = *(const float4*)(src + 4);
            float4 f2v = *(const float4*)(src + 8);
            float4 f3 = *(const float4*)(src + 12);
            uint4 o0, o1;
            o0.x = (unsigned)f2bf(f0.x) | ((unsigned)f2bf(f0.y) << 16);
            o0.y = (unsigned)f2bf(f0.z) | ((unsigned)f2bf(f0.w) << 16);
            o0.z = (unsigned)f2bf(f1.x) | ((unsigned)f2bf(f1.y) << 16);
            o0.w = (unsigned)f2bf(f1.z) | ((unsigned)f2bf(f1.w) << 16);
            o1.x = (unsigned)f2bf(f2v.x) | ((unsigned)f2bf(f2v.y) << 16);
            o1.y = (unsigned)f2bf(f2v.z) | ((unsigned)f2bf(f2v.w) << 16);
            o1.z = (unsigned)f2bf(f3.x) | ((unsigned)f2bf(f3.y) << 16);
            o1.w = (unsigned)f2bf(f3.z) | ((unsigned)f2bf(f3.w) << 16);
            *(uint4*)&sm.g.Bs[bd * 40 + bhalf * 16] = o0;
            *(uint4*)&sm.g.Bs[bd * 40 + bhalf * 16 + 8] = o1;
        }
        __syncthreads();
        short8 af[2];
#pragma unroll
        for (int i = 0; i < 2; ++i)
            af[i] = *(const short8*)&sm.g.As[(wave * 32 + i * 16 + mrow) * 40 + koff];
#pragma unroll
        for (int j = 0; j < 8; ++j) {
            short8 bfr = *(const short8*)&sm.g.Bs[(j * 16 + mrow) * 40 + koff];
#pragma unroll
            for (int i = 0; i < 2; ++i)
                acc[i][j] = __builtin_amdgcn_mfma_f32_16x16x32_bf16(
                    af[i], bfr, acc[i][j], 0, 0, 0);
        }
    }

    int lq = lane >> 4, lc = lane & 15;
#pragma unroll
    for (int j = 0; j < 8; ++j) {
        int d = j * 16 + lc;
#pragma unroll
        for (int i = 0; i < 2; ++i) {
#pragma unroll
            for (int r = 0; r < 4; ++r) {
                int row = wave * 32 + i * 16 + lq * 4 + r;
                G16[(n0 + row) * 768 + k * 128 + d] = f2bf(acc[i][j][r]);
            }
        }
    }
}

// ---------------------------------------------------------------------------
// k_knn: RESTRUCTURED for latency (the newly-identified ~35-40us kernel).
//  * 8 partitions/query, 2048 blocks x 32 queries: 8 blocks/CU (2x waves),
//    serial scan halved (~4.5 candidates/thread), finer load balance.
//  * merge FIRST (3 exact butterfly rounds over disjoint partition lists),
//    so the certified r=1 stop uses the TRUE 3x3 top-6 (d6~0.043 << margin)
//    -> ~90% of queries stop without the ring scan (the old per-thread
//    conservative stop failed ~half the time).
//  * done is group-uniform (all 8 lanes of a query have identical merged
//    lists) -> fallback branch and dedup re-merge are shuffle-safe.
//  * ring fallback keeps the proven per-lane early-break exactness argument;
//    final KNN_MERGE_D dedups by neighbor index (lists share the merged base).
// ---------------------------------------------------------------------------
__global__ void __launch_bounds__(256) k_knn(
    const float* __restrict__ loc,
    const unsigned short* __restrict__ ids,
    const int* __restrict__ starts,
    unsigned short* __restrict__ nbrs)
{
    __shared__ float2 xy_tmp[CN];
    __shared__ float2 xy_s[CN];
    __shared__ unsigned short ids_s[CN];
    __shared__ int st_s[257];
    int t = threadIdx.x;
    int b = blockIdx.x >> 5;                 // 32 blocks per batch
    int qbase = (blockIdx.x & 31) << 5;      // 32 queries per block
    const float2* lb = (const float2*)loc + b * CN;
#pragma unroll
    for (int r = 0; r < 4; ++r) {
        int p = t + r * 256;
        xy_tmp[p] = lb[p];
        ids_s[p] = ids[b * CN + p];
    }
    st_s[t] = starts[b * 257 + t];
    if (t == 0) st_s[256] = starts[b * 257 + 256];
    __syncthreads();
#pragma unroll
    for (int r = 0; r < 4; ++r) {
        int p = t + r * 256;
        xy_s[p] = xy_tmp[ids_s[p]];
    }
    __syncthreads();

    int qp = qbase + (t >> 3);               // sorted position of my query
    int pi = t & 7;                          // partition offset (8-way)
    int q = ids_s[qp];
    float2 qxy = xy_s[qp];
    float xq = qxy.x, yq = qxy.y;
    int cx = (int)(xq * 16.0f); cx = cx > 15 ? 15 : cx;
    int cy = (int)(yq * 16.0f); cy = cy > 15 ? 15 : cy;
    float dk[CK]; int ik[CK];
#pragma unroll
    for (int s = 0; s < CK; ++s) { dk[s] = 1e30f; ik[s] = 0x7FFFFFFF; }
    float dk5sq = __builtin_inff();
    const float h = 0.0625f;

#define KNN_CAND(P)                                                        \
    {                                                                      \
        float2 v = xy_s[P];                                                \
        float dx = __fsub_rn(v.x, xq);                                     \
        float dy = __fsub_rn(v.y, yq);                                     \
        float d2 = __fadd_rn(__fmul_rn(dx, dx), __fmul_rn(dy, dy));        \
        if (d2 < dk5sq) {                                                  \
            float ds = __fsqrt_rn(d2);                                     \
            int j = ids_s[P];                                              \
            if (ds < dk[CK - 1] || (ds == dk[CK - 1] && j < ik[CK - 1])) { \
                float dc = ds; int jc = j;                                 \
                _Pragma("unroll")                                          \
                for (int s = 0; s < CK; ++s) {                             \
                    bool sw = (dc < dk[s]) || (dc == dk[s] && jc < ik[s]); \
                    float od = dk[s]; int oi = ik[s];                      \
                    dk[s] = sw ? dc : od; ik[s] = sw ? jc : oi;            \
                    dc = sw ? od : dc;    jc = sw ? oi : jc;               \
                }                                                          \
                if (ik[CK - 1] != 0x7FFFFFFF)                              \
                    dk5sq = __fmul_rn(dk[CK - 1], dk[CK - 1]) * 1.000001f; \
            }                                                              \
        }                                                                  \
    }

// merge of DISJOINT partition lists (exact)
#define KNN_MERGE(MASK)                                                     \
    {                                                                       \
        float od[CK]; int oi[CK];                                           \
        _Pragma("unroll")                                                   \
        for (int s = 0; s < CK; ++s) {                                      \
            od[s] = __shfl_xor(dk[s], MASK);                                \
            oi[s] = __shfl_xor(ik[s], MASK);                                \
        }                                                                   \
        _Pragma("unroll")                                                   \
        for (int e = 0; e < CK; ++e) {                                      \
            float dc = od[e]; int jc = oi[e];                               \
            if ((dc < dk[CK - 1]) || (dc == dk[CK - 1] && jc < ik[CK - 1])) { \
                _Pragma("unroll")                                           \
                for (int s = 0; s < CK; ++s) {                              \
                    bool sw = (dc < dk[s]) || (dc == dk[s] && jc < ik[s]);  \
                    float td = dk[s]; int ti = ik[s];                       \
                    dk[s] = sw ? dc : td; ik[s] = sw ? jc : ti;             \
                    dc = sw ? td : dc;    jc = sw ? ti : jc;                \
                }                                                           \
            }                                                               \
        }                                                                   \
    }

// merge of possibly-OVERLAPPING lists: dedup by neighbor index (unique id)
#define KNN_MERGE_D(MASK)                                                   \
    {                                                                       \
        float od[CK]; int oi[CK];                                           \
        _Pragma("unroll")                                                   \
        for (int s = 0; s < CK; ++s) {                                      \
            od[s] = __shfl_xor(dk[s], MASK);                                \
            oi[s] = __shfl_xor(ik[s], MASK);                                \
        }                                                                   \
        _Pragma("unroll")                                                   \
        for (int e = 0; e < CK; ++e) {                                      \
            float dc = od[e]; int jc = oi[e];                               \
            bool dup = false;                                               \
            _Pragma("unroll")                                               \
            for (int s = 0; s < CK; ++s) dup = dup || (jc == ik[s]);        \
            if (!dup &&                                                     \
                ((dc < dk[CK - 1]) || (dc == dk[CK - 1] && jc < ik[CK - 1]))) { \
                _Pragma("unroll")                                           \
                for (int s = 0; s < CK; ++s) {                              \
                    bool sw = (dc < dk[s]) || (dc == dk[s] && jc < ik[s]);  \
                    float td = dk[s]; int ti = ik[s];                       \
                    dk[s] = sw ? dc : td; ik[s] = sw ? jc : ti;             \
                    dc = sw ? td : dc;    jc = sw ? ti : jc;                \
                }                                                           \
            }                                                               \
        }                                                                   \
    }

    // ---- fast path: 3x3 neighborhood = 3 contiguous sorted ranges
    {
        int yl = cy > 0 ? cy - 1 : 0, yh = cy < 15 ? cy + 1 : 15;
        int xl = cx > 0 ? cx - 1 : 0, xh = cx < 15 ? cx + 1 : 15;
        for (int yy = yl; yy <= yh; ++yy) {
            int p  = st_s[(yy << 4) + xl] + pi;
            int pe = st_s[(yy << 4) + xh + 1];
            for (; p < pe; p += 8) KNN_CAND(p)
        }
    }

    // ---- merge the 8 disjoint partition lists -> true top-6 of the 3x3
    KNN_MERGE(1)
    KNN_MERGE(2)
    KNN_MERGE(4)

    // ---- certified r=1 stop with the true top-6 (group-uniform)
    bool done;
    {
        int x0 = cx - 1, x1 = cx + 1, y0 = cy - 1, y1 = cy + 1;
        done = (x0 <= 0 && y0 <= 0 && x1 >= 15 && y1 >= 15);
        float mL = x0 > 0  ? __fsub_rn(xq, (float)x0 * h)       : 1e30f;
        float mR = x1 < 15 ? __fsub_rn((float)(x1 + 1) * h, xq) : 1e30f;
        float mB = y0 > 0  ? __fsub_rn(yq, (float)y0 * h)       : 1e30f;
        float mT = y1 < 15 ? __fsub_rn((float)(y1 + 1) * h, yq) : 1e30f;
        float bound = fminf(fminf(mL, mR), fminf(mB, mT)) * 0.999999f;
        done = done || (ik[CK - 1] != 0x7FFFFFFF && dk[CK - 1] < bound);
    }

    // ---- rare fallback (group-uniform entry): ring expansion from r=2.
    // Per-lane early break keeps the proven exactness argument (a lane stops
    // only when its >=true 6th certifies the box; unscanned cells then can't
    // contribute to the final merged top-6).
    if (!done) {
        if (ik[CK - 1] != 0x7FFFFFFF)
            dk5sq = __fmul_rn(dk[CK - 1], dk[CK - 1]) * 1.000001f;
        for (int r = 2; r < 16; ++r) {
            int x0 = cx - r, x1 = cx + r, y0 = cy - r, y1 = cy + r;
            int yl = y0 < 0 ? 0 : y0, yh = y1 > 15 ? 15 : y1;
            int xl = x0 < 0 ? 0 : x0, xh = x1 > 15 ? 15 : x1;
            for (int yy = yl; yy <= yh; ++yy) {
                bool ey = (yy == y0) || (yy == y1);
                if (ey) {
                    int p  = st_s[(yy << 4) + xl] + pi;
                    int pe = st_s[(yy << 4) + xh + 1];
                    for (; p < pe; p += 8) KNN_CAND(p)
                } else {
                    if (x0 >= 0) {
                        int p  = st_s[(yy << 4) + x0] + pi;
                        int pe = st_s[(yy << 4) + x0 + 1];
                        for (; p < pe; p += 8) KNN_CAND(p)
                    }
                    if (x1 <= 15) {
                        int p  = st_s[(yy << 4) + x1] + pi;
                        int pe = st_s[(yy << 4) + x1 + 1];
                        for (; p < pe; p += 8) KNN_CAND(p)
                    }
                }
            }
            if (x0 <= 0 && y0 <= 0 && x1 >= 15 && y1 >= 15) break;
            float mL = x0 > 0  ? __fsub_rn(xq, (float)x0 * h)       : 1e30f;
            float mR = x1 < 15 ? __fsub_rn((float)(x1 + 1) * h, xq) : 1e30f;
            float mB = y0 > 0  ? __fsub_rn(yq, (float)y0 * h)       : 1e30f;
            float mT = y1 < 15 ? __fsub_rn((float)(y1 + 1) * h, yq) : 1e30f;
            float bound = fminf(fminf(mL, mR), fminf(mB, mT)) * 0.999999f;
            if (ik[CK - 1] != 0x7FFFFFFF && dk[CK - 1] < bound) break;
        }
        // dedup re-merge (lists share the merged 3x3 base; ring finds unique)
        KNN_MERGE_D(1)
        KNN_MERGE_D(2)
        KNN_MERGE_D(4)
    }
#undef KNN_CAND
#undef KNN_MERGE
#undef KNN_MERGE_D

    if (pi == 0) {
        unsigned short* o = nbrs + (unsigned)(b * CN + q) * CK;
#pragma unroll
        for (int s = 0; s < CK; ++s) o[s] = (unsigned short)ik[s];
    }
}

// ---------------------------------------------------------------------------
// k_gather: bf16-G version, proven r10 (bit-identical).
// ---------------------------------------------------------------------------
__global__ void __launch_bounds__(256) k_gather(
    const float* __restrict__ loc,
    const float* __restrict__ dl,
    const unsigned short* __restrict__ nbrs,
    const unsigned short* __restrict__ ids,
    const unsigned short* __restrict__ G16,
    const float* __restrict__ W3d,
    const float* __restrict__ b3d,
    const float* __restrict__ bnb,
    float* __restrict__ outh,          // [64][1025][128]
    float* __restrict__ partials)      // [1024][128]
{
    __shared__ float psum[4][CD];
    __shared__ unsigned short nbs[64 * CK];   // neighbor lists, segment order
    __shared__ unsigned short nloc[64];       // original row index per slot
    int t = threadIdx.x, bx = blockIdx.x;
    int b = bx >> 4;                          // 16 blocks per batch
    int qbase = (bx & 15) << 6;               // 64 sorted positions per block

    if (t < 32)
        ((unsigned*)nloc)[t] = ((const unsigned*)(ids + b * CN + qbase))[t];
    __syncthreads();
    if (t < 64) {
        int n = nloc[t];
        const unsigned short* src = nbrs + ((size_t)(b << 10) + n) * CK;
#pragma unroll
        for (int s = 0; s < CK; ++s) nbs[t * CK + s] = src[s];
    }

    int d8 = t & 15, rg = t >> 4;             // 16 d-groups x 16 row-groups
    int d0 = d8 * 8;
    float w0[8], w1[8], w2[8], bias[8];
#pragma unroll
    for (int dd = 0; dd < 8; ++dd) {
        int d = d0 + dd;
        w0[dd] = W3d[d * 3];
        w1[dd] = W3d[d * 3 + 1];
        w2[dd] = W3d[d * 3 + 2];
        bias[dd] = b3d[d] + bnb[d];
    }
    float csum[8];
#pragma unroll
    for (int dd = 0; dd < 8; ++dd) csum[dd] = 0.f;
    __syncthreads();

#pragma unroll
    for (int rr = 0; rr < 2; ++rr) {
        int r0 = rr * 32 + rg;               // slots rg, 32+rg
        int r1 = r0 + 16;                    // slots 16+rg, 48+rg
        int n0s = nloc[r0], n1s = nloc[r1];  // original row indices
        int gr0 = (b << 10) + n0s, gr1 = (b << 10) + n1s;
        const unsigned short* nA = nbs + r0 * CK;
        const unsigned short* nB = nbs + r1 * CK;
        // ---- issue all 12 bf16x8 gathers + 4 small loads, named ----
        uint4 ga0 = *(const uint4*)(G16 + nA[0] * 768 + 0 * 128 + d0);
        uint4 ga1 = *(const uint4*)(G16 + nA[1] * 768 + 1 * 128 + d0);
        uint4 ga2 = *(const uint4*)(G16 + nA[2] * 768 + 2 * 128 + d0);
        uint4 ga3 = *(const uint4*)(G16 + nA[3] * 768 + 3 * 128 + d0);
        uint4 ga4 = *(const uint4*)(G16 + nA[4] * 768 + 4 * 128 + d0);
        uint4 ga5 = *(const uint4*)(G16 + nA[5] * 768 + 5 * 128 + d0);
        uint4 gb0 = *(const uint4*)(G16 + nB[0] * 768 + 0 * 128 + d0);
        uint4 gb1 = *(const uint4*)(G16 + nB[1] * 768 + 1 * 128 + d0);
        uint4 gb2 = *(const uint4*)(G16 + nB[2] * 768 + 2 * 128 + d0);
        uint4 gb3 = *(const uint4*)(G16 + nB[3] * 768 + 3 * 128 + d0);
        uint4 gb4 = *(const uint4*)(G16 + nB[4] * 768 + 4 * 128 + d0);
        uint4 gb5 = *(const uint4*)(G16 + nB[5] * 768 + 5 * 128 + d0);
        float2 lA = ((const float2*)loc)[gr0];
        float2 lB = ((const float2*)loc)[gr1];
        float dA = dl[gr0];
        float dB = dl[gr1];
        // ---- consume row 0 (k-ascending sum order preserved) ----
        {
            float o[8];
#pragma unroll
            for (int dd = 0; dd < 8; ++dd) {
                float a = ((((bfe(ga0, dd) + bfe(ga1, dd)) + bfe(ga2, dd))
                           + bfe(ga3, dd)) + bfe(ga4, dd)) + bfe(ga5, dd);
                float v = a + bias[dd] + lA.x * w0[dd] + lA.y * w1[dd]
                        + dA * w2[dd];
                o[dd] = v >= 0.f ? v : 0.01f * v;
                csum[dd] += o[dd];
            }
            float* ob = outh + ((long)b * 1025 + n0s + 1) * 128 + d0;
            float4 s0, s1;
            s0.x = o[0]; s0.y = o[1]; s0.z = o[2]; s0.w = o[3];
            s1.x = o[4]; s1.y = o[5]; s1.z = o[6]; s1.w = o[7];
            *(float4*)(ob) = s0;
            *(float4*)(ob + 4) = s1;
        }
        // ---- consume row 1 ----
        {
            float o[8];
#pragma unroll
            for (int dd = 0; dd < 8; ++dd) {
                float a = ((((bfe(gb0, dd) + bfe(gb1, dd)) + bfe(gb2, dd))
                           + bfe(gb3, dd)) + bfe(gb4, dd)) + bfe(gb5, dd);
                float v = a + bias[dd] + lB.x * w0[dd] + lB.y * w1[dd]
                        + dB * w2[dd];
                o[dd] = v >= 0.f ? v : 0.01f * v;
                csum[dd] += o[dd];
            }
            float* ob = outh + ((long)b * 1025 + n1s + 1) * 128 + d0;
            float4 s0, s1;
            s0.x = o[0]; s0.y = o[1]; s0.z = o[2]; s0.w = o[3];
            s1.x = o[4]; s1.y = o[5]; s1.z = o[6]; s1.w = o[7];
            *(float4*)(ob) = s0;
            *(float4*)(ob + 4) = s1;
        }
    }

    // within wave: lanes t, t+16, t+32, t+48 share d8 (4 row-groups)
#pragma unroll
    for (int dd = 0; dd < 8; ++dd) {
        csum[dd] += __shfl_xor(csum[dd], 16);
        csum[dd] += __shfl_xor(csum[dd], 32);
    }
    int wave = t >> 6, lane = t & 63;
    if (lane < 16) {
#pragma unroll
        for (int dd = 0; dd < 8; ++dd) psum[wave][d0 + dd] = csum[dd];
    }
    __syncthreads();
    if (t < CD)
        partials[(bx << 7) + t] =
            psum[0][t] + psum[1][t] + psum[2][t] + psum[3][t];
}

// ---------------------------------------------------------------------------
// k_fin: reduce 16 block-partials/batch + depot row + mean/1025.
// ---------------------------------------------------------------------------
__global__ void k_fin(const float* __restrict__ depot,
                      const float* __restrict__ Wdep,
                      const float* __restrict__ bdep,
                      const float* __restrict__ partials,
                      float* __restrict__ out) {
    int idx = blockIdx.x * 256 + threadIdx.x;   // 64*128
    int b = idx >> 7, d = idx & 127;
    float acc = 0.f;
#pragma unroll
    for (int g = 0; g < 16; ++g) acc += partials[(b * 16 + g) * 128 + d];
    float dv = depot[b * 2] * Wdep[d * 2] + depot[b * 2 + 1] * Wdep[d * 2 + 1] + bdep[d];
    float lr = dv >= 0.f ? dv : 0.01f * dv;
    out[(long)b * 1025 * 128 + d] = lr;
    out[(long)CB * 1025 * 128 + idx] = (acc + lr) * (1.0f / 1025.0f);
}

extern "C" void kernel_launch(void* const* d_in, const int* in_sizes, int n_in,
                              void* d_out, int out_size, void* d_ws, size_t ws_size,
                              hipStream_t stream) {
    const float* loc      = (const float*)d_in[0];
    const float* deadline = (const float*)d_in[1];
    const float* depot    = (const float*)d_in[2];
    const float* W3d      = (const float*)d_in[3];
    const float* b3d      = (const float*)d_in[4];
    const float* W2d      = (const float*)d_in[5];
    const float* b2d      = (const float*)d_in[6];
    const float* Wnb      = (const float*)d_in[7];
    const float* bnb      = (const float*)d_in[8];
    const float* Wdep     = (const float*)d_in[9];
    const float* bdep     = (const float*)d_in[10];
    float* out = (float*)d_out;

    char* ws = (char*)d_ws;
    unsigned short* G16   = (unsigned short*)(ws + WS_G);
    unsigned short* nbrs  = (unsigned short*)(ws + WS_NBRS);
    unsigned short* ids   = (unsigned short*)(ws + WS_IDS);
    int* starts           = (int*)(ws + WS_STARTS);
    float* partials       = (float*)(ws + WS_PART);

    k_gridg<<<112, 256, 0, stream>>>(loc, W2d, b2d, Wnb, ids, starts, G16);
    k_knn<<<2048, 256, 0, stream>>>(loc, ids, starts, nbrs);
    k_gather<<<1024, 256, 0, stream>>>(loc, deadline, nbrs, ids, G16, W3d,
                                       b3d, bnb, out, partials);
    k_fin<<<32, 256, 0, stream>>>(depot, Wdep, bdep, partials, out);
}

// Round 13
// 130.667 us; speedup vs baseline: 1.0923x; 1.0007x over previous
//
#include <hip/hip_runtime.h>
#include <hip/hip_bf16.h>

// Problem constants (B=64, N=1024, D=128, K=6)
#define CB 64
#define CN 1024
#define CD 128
#define CK 6

typedef __attribute__((ext_vector_type(8))) short short8;
typedef __attribute__((ext_vector_type(4))) float floatx4;

__device__ __forceinline__ unsigned short f2bf(float f) {
    union { float f; unsigned u; } c; c.f = f;
    unsigned u = c.u;
    u += 0x7FFFu + ((u >> 16) & 1u);
    return (unsigned short)(u >> 16);
}
__device__ __forceinline__ float bf2f(unsigned short u) {
    union { unsigned u; float f; } c; c.u = ((unsigned)u) << 16; return c.f;
}
// element dd (0..7) of a uint4 holding 8 bf16
__device__ __forceinline__ float bfe(const uint4& g, int dd) {
    unsigned w = (&g.x)[dd >> 1];
    unsigned short h = (dd & 1) ? (unsigned short)(w >> 16)
                                : (unsigned short)(w & 0xFFFFu);
    return bf2f(h);
}

// ws layout (bytes) — ws is 256 MiB
#define WS_G      0          // [1024][6][128] bf16 = 1.5 MB (G16[m][k][d])
#define WS_NBRS   3145728    // [65536][6] u16 = 768 KB
#define WS_IDS    3932160    // [64][1024] u16 = 128 KB
#define WS_STARTS 4063232    // [64][257] i32 = 64.25 KB
#define WS_PART   4129024    // [1024][128] f32 = 512 KB
#define WS_XYS    4653312    // [64][1024] float2 = 512 KB (sorted coords)

struct SortSM { float2 pts[CN]; int cnt[256]; int base[256]; };
struct GSM    { unsigned short As[128 * 40]; unsigned short Bs[128 * 40]; };
union GridSM  { SortSM s; GSM g; };

// ---------------------------------------------------------------------------
// k_gridg: blocks 0..63 = per-batch counting sort (now ALSO emits the sorted
// coordinate array xys[b][pos] during scatter — knn no longer needs its
// LDS permute pass); blocks 64..111 = G precompute (bf16). Proven r10/r12.
// ---------------------------------------------------------------------------
__global__ void __launch_bounds__(256) k_gridg(
    const float* __restrict__ loc,
    const float* __restrict__ W2d,
    const float* __restrict__ b2d,
    const float* __restrict__ Wnb,
    unsigned short* __restrict__ ids,
    int* __restrict__ starts,
    unsigned short* __restrict__ G16,
    float2* __restrict__ xys)
{
    __shared__ GridSM sm;
    int t = threadIdx.x;

    if (blockIdx.x < 64) {
        int b = blockIdx.x;
        const float2* lb = (const float2*)loc + b * CN;
#pragma unroll
        for (int r = 0; r < 4; ++r) sm.s.pts[t + r * 256] = lb[t + r * 256];
        sm.s.cnt[t] = 0;
        __syncthreads();
        int mycell[4];
#pragma unroll
        for (int r = 0; r < 4; ++r) {
            float2 p = sm.s.pts[t * 4 + r];
            int cx = (int)(p.x * 16.0f); cx = cx > 15 ? 15 : cx;
            int cy = (int)(p.y * 16.0f); cy = cy > 15 ? 15 : cy;
            mycell[r] = (cy << 4) + cx;
            atomicAdd(&sm.s.cnt[mycell[r]], 1);
        }
        __syncthreads();
        for (int off = 1; off < 256; off <<= 1) {
            int u = (t >= off) ? sm.s.cnt[t - off] : 0;
            __syncthreads();
            sm.s.cnt[t] += u;
            __syncthreads();
        }
        int excl = (t == 0) ? 0 : sm.s.cnt[t - 1];
        sm.s.base[t] = excl;
        starts[b * 257 + t] = excl;
        if (t == 255) starts[b * 257 + 256] = sm.s.cnt[255];
        __syncthreads();
#pragma unroll
        for (int r = 0; r < 4; ++r) {
            int pos = atomicAdd(&sm.s.base[mycell[r]], 1);
            ids[b * CN + pos] = (unsigned short)(t * 4 + r);
            xys[(b << 10) + pos] = sm.s.pts[t * 4 + r];
        }
        return;
    }

    int gb = blockIdx.x - 64;          // 0..47
    int k = gb % 6;
    int tile = gb / 6;                 // 0..7
    int n0 = tile << 7;                // 128 rows per tile

    int wave = t >> 6, lane = t & 63;
    int koff = (lane >> 4) * 8;
    int mrow = lane & 15;

    int e2 = t & 15, rg = t >> 4;
    float2 pl[8];
#pragma unroll
    for (int rr = 0; rr < 8; ++rr)
        pl[rr] = ((const float2*)loc)[n0 + rg + rr * 16];

    int bd = t >> 1, bhalf = t & 1;

    floatx4 acc[2][8];
#pragma unroll
    for (int i = 0; i < 2; ++i)
#pragma unroll
        for (int j = 0; j < 8; ++j) acc[i][j] = (floatx4){0.f, 0.f, 0.f, 0.f};

#pragma unroll
    for (int c = 0; c < 4; ++c) {
        __syncthreads();
        {
            int e0 = c * 32 + e2 * 2;
            float wx0 = W2d[e0 * 2],     wy0 = W2d[e0 * 2 + 1], bz0 = b2d[e0];
            float wx1 = W2d[e0 * 2 + 2], wy1 = W2d[e0 * 2 + 3], bz1 = b2d[e0 + 1];
#pragma unroll
            for (int rr = 0; rr < 8; ++rr) {
                float2 p = pl[rr];
                float v0 = fmaf(p.x, wx0, fmaf(p.y, wy0, bz0));
                float v1 = fmaf(p.x, wx1, fmaf(p.y, wy1, bz1));
                unsigned pack = (unsigned)f2bf(v0) | ((unsigned)f2bf(v1) << 16);
                *(unsigned*)&sm.g.As[(rg + rr * 16) * 40 + e2 * 2] = pack;
            }
        }
        {
            const float* src = Wnb + bd * 768 + k * 128 + c * 32 + bhalf * 16;
            float4 f0 = *(const float4*)(src);
            float4 f1 = *(const float4*)(src + 4);
            float4 f2v = *(const float4*)(src + 8);
            float4 f3 = *(const float4*)(src + 12);
            uint4 o0, o1;
            o0.x = (unsigned)f2bf(f0.x) | ((unsigned)f2bf(f0.y) << 16);
            o0.y = (unsigned)f2bf(f0.z) | ((unsigned)f2bf(f0.w) << 16);
            o0.z = (unsigned)f2bf(f1.x) | ((unsigned)f2bf(f1.y) << 16);
            o0.w = (unsigned)f2bf(f1.z) | ((unsigned)f2bf(f1.w) << 16);
            o1.x = (unsigned)f2bf(f2v.x) | ((unsigned)f2bf(f2v.y) << 16);
            o1.y = (unsigned)f2bf(f2v.z) | ((unsigned)f2bf(f2v.w) << 16);
            o1.z = (unsigned)f2bf(f3.x) | ((unsigned)f2bf(f3.y) << 16);
            o1.w = (unsigned)f2bf(f3.z) | ((unsigned)f2bf(f3.w) << 16);
            *(uint4*)&sm.g.Bs[bd * 40 + bhalf * 16] = o0;
            *(uint4*)&sm.g.Bs[bd * 40 + bhalf * 16 + 8] = o1;
        }
        __syncthreads();
        short8 af[2];
#pragma unroll
        for (int i = 0; i < 2; ++i)
            af[i] = *(const short8*)&sm.g.As[(wave * 32 + i * 16 + mrow) * 40 + koff];
#pragma unroll
        for (int j = 0; j < 8; ++j) {
            short8 bfr = *(const short8*)&sm.g.Bs[(j * 16 + mrow) * 40 + koff];
#pragma unroll
            for (int i = 0; i < 2; ++i)
                acc[i][j] = __builtin_amdgcn_mfma_f32_16x16x32_bf16(
                    af[i], bfr, acc[i][j], 0, 0, 0);
        }
    }

    int lq = lane >> 4, lc = lane & 15;
#pragma unroll
    for (int j = 0; j < 8; ++j) {
        int d = j * 16 + lc;
#pragma unroll
        for (int i = 0; i < 2; ++i) {
#pragma unroll
            for (int r = 0; r < 4; ++r) {
                int row = wave * 32 + i * 16 + lq * 4 + r;
                G16[(n0 + row) * 768 + k * 128 + d] = f2bf(acc[i][j][r]);
            }
        }
    }
}

// ---------------------------------------------------------------------------
// k_knn: r12-proven scan/merge logic with cheaper staging:
//  * sorted coords loaded DIRECTLY from xys (gridg emits them) — no LDS
//    permute pass, no xy_tmp (8 KB LDS saved), one fewer barrier.
//  * 512-thread blocks, 64 queries each (1024 blocks): halves the redundant
//    per-block batch staging while keeping 8 partitions/query and full
//    32-wave/CU occupancy (8 waves x 4 blocks).
// Scan/merge/fallback arithmetic is byte-identical to r12 (passed, exact).
// ---------------------------------------------------------------------------
__global__ void __launch_bounds__(512) k_knn(
    const float2* __restrict__ xys,
    const unsigned short* __restrict__ ids,
    const int* __restrict__ starts,
    unsigned short* __restrict__ nbrs)
{
    __shared__ float2 xy_s[CN];              // 8 KB (sorted order, direct)
    __shared__ unsigned short ids_s[CN];     // 2 KB
    __shared__ int st_s[257];                // 1 KB
    int t = threadIdx.x;
    int b = blockIdx.x >> 4;                 // 16 blocks per batch
    int qbase = (blockIdx.x & 15) << 6;      // 64 queries per block

    ((unsigned*)ids_s)[t] = ((const unsigned*)(ids + b * CN))[t];   // 1024 u16
    xy_s[t]       = xys[(b << 10) + t];
    xy_s[t + 512] = xys[(b << 10) + t + 512];
    if (t < 257) st_s[t] = starts[b * 257 + t];
    __syncthreads();

    int qp = qbase + (t >> 3);               // sorted position of my query
    int pi = t & 7;                          // partition offset (8-way)
    int q = ids_s[qp];
    float2 qxy = xy_s[qp];
    float xq = qxy.x, yq = qxy.y;
    int cx = (int)(xq * 16.0f); cx = cx > 15 ? 15 : cx;
    int cy = (int)(yq * 16.0f); cy = cy > 15 ? 15 : cy;
    float dk[CK]; int ik[CK];
#pragma unroll
    for (int s = 0; s < CK; ++s) { dk[s] = 1e30f; ik[s] = 0x7FFFFFFF; }
    float dk5sq = __builtin_inff();
    const float h = 0.0625f;

#define KNN_CAND(P)                                                        \
    {                                                                      \
        float2 v = xy_s[P];                                                \
        float dx = __fsub_rn(v.x, xq);                                     \
        float dy = __fsub_rn(v.y, yq);                                     \
        float d2 = __fadd_rn(__fmul_rn(dx, dx), __fmul_rn(dy, dy));        \
        if (d2 < dk5sq) {                                                  \
            float ds = __fsqrt_rn(d2);                                     \
            int j = ids_s[P];                                              \
            if (ds < dk[CK - 1] || (ds == dk[CK - 1] && j < ik[CK - 1])) { \
                float dc = ds; int jc = j;                                 \
                _Pragma("unroll")                                          \
                for (int s = 0; s < CK; ++s) {                             \
                    bool sw = (dc < dk[s]) || (dc == dk[s] && jc < ik[s]); \
                    float od = dk[s]; int oi = ik[s];                      \
                    dk[s] = sw ? dc : od; ik[s] = sw ? jc : oi;            \
                    dc = sw ? od : dc;    jc = sw ? oi : jc;               \
                }                                                          \
                if (ik[CK - 1] != 0x7FFFFFFF)                              \
                    dk5sq = __fmul_rn(dk[CK - 1], dk[CK - 1]) * 1.000001f; \
            }                                                              \
        }                                                                  \
    }

// merge of DISJOINT partition lists (exact)
#define KNN_MERGE(MASK)                                                     \
    {                                                                       \
        float od[CK]; int oi[CK];                                           \
        _Pragma("unroll")                                                   \
        for (int s = 0; s < CK; ++s) {                                      \
            od[s] = __shfl_xor(dk[s], MASK);                                \
            oi[s] = __shfl_xor(ik[s], MASK);                                \
        }                                                                   \
        _Pragma("unroll")                                                   \
        for (int e = 0; e < CK; ++e) {                                      \
            float dc = od[e]; int jc = oi[e];                               \
            if ((dc < dk[CK - 1]) || (dc == dk[CK - 1] && jc < ik[CK - 1])) { \
                _Pragma("unroll")                                           \
                for (int s = 0; s < CK; ++s) {                              \
                    bool sw = (dc < dk[s]) || (dc == dk[s] && jc < ik[s]);  \
                    float td = dk[s]; int ti = ik[s];                       \
                    dk[s] = sw ? dc : td; ik[s] = sw ? jc : ti;             \
                    dc = sw ? td : dc;    jc = sw ? ti : jc;                \
                }                                                           \
            }                                                               \
        }                                                                   \
    }

// merge of possibly-OVERLAPPING lists: dedup by neighbor index (unique id)
#define KNN_MERGE_D(MASK)                                                   \
    {                                                                       \
        float od[CK]; int oi[CK];                                           \
        _Pragma("unroll")                                                   \
        for (int s = 0; s < CK; ++s) {                                      \
            od[s] = __shfl_xor(dk[s], MASK);                                \
            oi[s] = __shfl_xor(ik[s], MASK);                                \
        }                                                                   \
        _Pragma("unroll")                                                   \
        for (int e = 0; e < CK; ++e) {                                      \
            float dc = od[e]; int jc = oi[e];                               \
            bool dup = false;                                               \
            _Pragma("unroll")                                               \
            for (int s = 0; s < CK; ++s) dup = dup || (jc == ik[s]);        \
            if (!dup &&                                                     \
                ((dc < dk[CK - 1]) || (dc == dk[CK - 1] && jc < ik[CK - 1]))) { \
                _Pragma("unroll")                                           \
                for (int s = 0; s < CK; ++s) {                              \
                    bool sw = (dc < dk[s]) || (dc == dk[s] && jc < ik[s]);  \
                    float td = dk[s]; int ti = ik[s];                       \
                    dk[s] = sw ? dc : td; ik[s] = sw ? jc : ti;             \
                    dc = sw ? td : dc;    jc = sw ? ti : jc;                \
                }                                                           \
            }                                                               \
        }                                                                   \
    }

    // ---- fast path: 3x3 neighborhood = 3 contiguous sorted ranges
    {
        int yl = cy > 0 ? cy - 1 : 0, yh = cy < 15 ? cy + 1 : 15;
        int xl = cx > 0 ? cx - 1 : 0, xh = cx < 15 ? cx + 1 : 15;
        for (int yy = yl; yy <= yh; ++yy) {
            int p  = st_s[(yy << 4) + xl] + pi;
            int pe = st_s[(yy << 4) + xh + 1];
            for (; p < pe; p += 8) KNN_CAND(p)
        }
    }

    // ---- merge the 8 disjoint partition lists -> true top-6 of the 3x3
    KNN_MERGE(1)
    KNN_MERGE(2)
    KNN_MERGE(4)

    // ---- certified r=1 stop with the true top-6 (group-uniform)
    bool done;
    {
        int x0 = cx - 1, x1 = cx + 1, y0 = cy - 1, y1 = cy + 1;
        done = (x0 <= 0 && y0 <= 0 && x1 >= 15 && y1 >= 15);
        float mL = x0 > 0  ? __fsub_rn(xq, (float)x0 * h)       : 1e30f;
        float mR = x1 < 15 ? __fsub_rn((float)(x1 + 1) * h, xq) : 1e30f;
        float mB = y0 > 0  ? __fsub_rn(yq, (float)y0 * h)       : 1e30f;
        float mT = y1 < 15 ? __fsub_rn((float)(y1 + 1) * h, yq) : 1e30f;
        float bound = fminf(fminf(mL, mR), fminf(mB, mT)) * 0.999999f;
        done = done || (ik[CK - 1] != 0x7FFFFFFF && dk[CK - 1] < bound);
    }

    // ---- rare fallback (group-uniform entry): ring expansion from r=2
    if (!done) {
        if (ik[CK - 1] != 0x7FFFFFFF)
            dk5sq = __fmul_rn(dk[CK - 1], dk[CK - 1]) * 1.000001f;
        for (int r = 2; r < 16; ++r) {
            int x0 = cx - r, x1 = cx + r, y0 = cy - r, y1 = cy + r;
            int yl = y0 < 0 ? 0 : y0, yh = y1 > 15 ? 15 : y1;
            int xl = x0 < 0 ? 0 : x0, xh = x1 > 15 ? 15 : x1;
            for (int yy = yl; yy <= yh; ++yy) {
                bool ey = (yy == y0) || (yy == y1);
                if (ey) {
                    int p  = st_s[(yy << 4) + xl] + pi;
                    int pe = st_s[(yy << 4) + xh + 1];
                    for (; p < pe; p += 8) KNN_CAND(p)
                } else {
                    if (x0 >= 0) {
                        int p  = st_s[(yy << 4) + x0] + pi;
                        int pe = st_s[(yy << 4) + x0 + 1];
                        for (; p < pe; p += 8) KNN_CAND(p)
                    }
                    if (x1 <= 15) {
                        int p  = st_s[(yy << 4) + x1] + pi;
                        int pe = st_s[(yy << 4) + x1 + 1];
                        for (; p < pe; p += 8) KNN_CAND(p)
                    }
                }
            }
            if (x0 <= 0 && y0 <= 0 && x1 >= 15 && y1 >= 15) break;
            float mL = x0 > 0  ? __fsub_rn(xq, (float)x0 * h)       : 1e30f;
            float mR = x1 < 15 ? __fsub_rn((float)(x1 + 1) * h, xq) : 1e30f;
            float mB = y0 > 0  ? __fsub_rn(yq, (float)y0 * h)       : 1e30f;
            float mT = y1 < 15 ? __fsub_rn((float)(y1 + 1) * h, yq) : 1e30f;
            float bound = fminf(fminf(mL, mR), fminf(mB, mT)) * 0.999999f;
            if (ik[CK - 1] != 0x7FFFFFFF && dk[CK - 1] < bound) break;
        }
        KNN_MERGE_D(1)
        KNN_MERGE_D(2)
        KNN_MERGE_D(4)
    }
#undef KNN_CAND
#undef KNN_MERGE
#undef KNN_MERGE_D

    if (pi == 0) {
        unsigned short* o = nbrs + (unsigned)(b * CN + q) * CK;
#pragma unroll
        for (int s = 0; s < CK; ++s) o[s] = (unsigned short)ik[s];
    }
}

// ---------------------------------------------------------------------------
// k_gather: bf16-G version, proven r10/r12 (bit-identical).
// ---------------------------------------------------------------------------
__global__ void __launch_bounds__(256) k_gather(
    const float* __restrict__ loc,
    const float* __restrict__ dl,
    const unsigned short* __restrict__ nbrs,
    const unsigned short* __restrict__ ids,
    const unsigned short* __restrict__ G16,
    const float* __restrict__ W3d,
    const float* __restrict__ b3d,
    const float* __restrict__ bnb,
    float* __restrict__ outh,          // [64][1025][128]
    float* __restrict__ partials)      // [1024][128]
{
    __shared__ float psum[4][CD];
    __shared__ unsigned short nbs[64 * CK];   // neighbor lists, segment order
    __shared__ unsigned short nloc[64];       // original row index per slot
    int t = threadIdx.x, bx = blockIdx.x;
    int b = bx >> 4;                          // 16 blocks per batch
    int qbase = (bx & 15) << 6;               // 64 sorted positions per block

    if (t < 32)
        ((unsigned*)nloc)[t] = ((const unsigned*)(ids + b * CN + qbase))[t];
    __syncthreads();
    if (t < 64) {
        int n = nloc[t];
        const unsigned short* src = nbrs + ((size_t)(b << 10) + n) * CK;
#pragma unroll
        for (int s = 0; s < CK; ++s) nbs[t * CK + s] = src[s];
    }

    int d8 = t & 15, rg = t >> 4;             // 16 d-groups x 16 row-groups
    int d0 = d8 * 8;
    float w0[8], w1[8], w2[8], bias[8];
#pragma unroll
    for (int dd = 0; dd < 8; ++dd) {
        int d = d0 + dd;
        w0[dd] = W3d[d * 3];
        w1[dd] = W3d[d * 3 + 1];
        w2[dd] = W3d[d * 3 + 2];
        bias[dd] = b3d[d] + bnb[d];
    }
    float csum[8];
#pragma unroll
    for (int dd = 0; dd < 8; ++dd) csum[dd] = 0.f;
    __syncthreads();

#pragma unroll
    for (int rr = 0; rr < 2; ++rr) {
        int r0 = rr * 32 + rg;               // slots rg, 32+rg
        int r1 = r0 + 16;                    // slots 16+rg, 48+rg
        int n0s = nloc[r0], n1s = nloc[r1];  // original row indices
        int gr0 = (b << 10) + n0s, gr1 = (b << 10) + n1s;
        const unsigned short* nA = nbs + r0 * CK;
        const unsigned short* nB = nbs + r1 * CK;
        // ---- issue all 12 bf16x8 gathers + 4 small loads, named ----
        uint4 ga0 = *(const uint4*)(G16 + nA[0] * 768 + 0 * 128 + d0);
        uint4 ga1 = *(const uint4*)(G16 + nA[1] * 768 + 1 * 128 + d0);
        uint4 ga2 = *(const uint4*)(G16 + nA[2] * 768 + 2 * 128 + d0);
        uint4 ga3 = *(const uint4*)(G16 + nA[3] * 768 + 3 * 128 + d0);
        uint4 ga4 = *(const uint4*)(G16 + nA[4] * 768 + 4 * 128 + d0);
        uint4 ga5 = *(const uint4*)(G16 + nA[5] * 768 + 5 * 128 + d0);
        uint4 gb0 = *(const uint4*)(G16 + nB[0] * 768 + 0 * 128 + d0);
        uint4 gb1 = *(const uint4*)(G16 + nB[1] * 768 + 1 * 128 + d0);
        uint4 gb2 = *(const uint4*)(G16 + nB[2] * 768 + 2 * 128 + d0);
        uint4 gb3 = *(const uint4*)(G16 + nB[3] * 768 + 3 * 128 + d0);
        uint4 gb4 = *(const uint4*)(G16 + nB[4] * 768 + 4 * 128 + d0);
        uint4 gb5 = *(const uint4*)(G16 + nB[5] * 768 + 5 * 128 + d0);
        float2 lA = ((const float2*)loc)[gr0];
        float2 lB = ((const float2*)loc)[gr1];
        float dA = dl[gr0];
        float dB = dl[gr1];
        // ---- consume row 0 (k-ascending sum order preserved) ----
        {
            float o[8];
#pragma unroll
            for (int dd = 0; dd < 8; ++dd) {
                float a = ((((bfe(ga0, dd) + bfe(ga1, dd)) + bfe(ga2, dd))
                           + bfe(ga3, dd)) + bfe(ga4, dd)) + bfe(ga5, dd);
                float v = a + bias[dd] + lA.x * w0[dd] + lA.y * w1[dd]
                        + dA * w2[dd];
                o[dd] = v >= 0.f ? v : 0.01f * v;
                csum[dd] += o[dd];
            }
            float* ob = outh + ((long)b * 1025 + n0s + 1) * 128 + d0;
            float4 s0, s1;
            s0.x = o[0]; s0.y = o[1]; s0.z = o[2]; s0.w = o[3];
            s1.x = o[4]; s1.y = o[5]; s1.z = o[6]; s1.w = o[7];
            *(float4*)(ob) = s0;
            *(float4*)(ob + 4) = s1;
        }
        // ---- consume row 1 ----
        {
            float o[8];
#pragma unroll
            for (int dd = 0; dd < 8; ++dd) {
                float a = ((((bfe(gb0, dd) + bfe(gb1, dd)) + bfe(gb2, dd))
                           + bfe(gb3, dd)) + bfe(gb4, dd)) + bfe(gb5, dd);
                float v = a + bias[dd] + lB.x * w0[dd] + lB.y * w1[dd]
                        + dB * w2[dd];
                o[dd] = v >= 0.f ? v : 0.01f * v;
                csum[dd] += o[dd];
            }
            float* ob = outh + ((long)b * 1025 + n1s + 1) * 128 + d0;
            float4 s0, s1;
            s0.x = o[0]; s0.y = o[1]; s0.z = o[2]; s0.w = o[3];
            s1.x = o[4]; s1.y = o[5]; s1.z = o[6]; s1.w = o[7];
            *(float4*)(ob) = s0;
            *(float4*)(ob + 4) = s1;
        }
    }

    // within wave: lanes t, t+16, t+32, t+48 share d8 (4 row-groups)
#pragma unroll
    for (int dd = 0; dd < 8; ++dd) {
        csum[dd] += __shfl_xor(csum[dd], 16);
        csum[dd] += __shfl_xor(csum[dd], 32);
    }
    int wave = t >> 6, lane = t & 63;
    if (lane < 16) {
#pragma unroll
        for (int dd = 0; dd < 8; ++dd) psum[wave][d0 + dd] = csum[dd];
    }
    __syncthreads();
    if (t < CD)
        partials[(bx << 7) + t] =
            psum[0][t] + psum[1][t] + psum[2][t] + psum[3][t];
}

// ---------------------------------------------------------------------------
// k_fin: reduce 16 block-partials/batch + depot row + mean/1025.
// ---------------------------------------------------------------------------
__global__ void k_fin(const float* __restrict__ depot,
                      const float* __restrict__ Wdep,
                      const float* __restrict__ bdep,
                      const float* __restrict__ partials,
                      float* __restrict__ out) {
    int idx = blockIdx.x * 256 + threadIdx.x;   // 64*128
    int b = idx >> 7, d = idx & 127;
    float acc = 0.f;
#pragma unroll
    for (int g = 0; g < 16; ++g) acc += partials[(b * 16 + g) * 128 + d];
    float dv = depot[b * 2] * Wdep[d * 2] + depot[b * 2 + 1] * Wdep[d * 2 + 1] + bdep[d];
    float lr = dv >= 0.f ? dv : 0.01f * dv;
    out[(long)b * 1025 * 128 + d] = lr;
    out[(long)CB * 1025 * 128 + idx] = (acc + lr) * (1.0f / 1025.0f);
}

extern "C" void kernel_launch(void* const* d_in, const int* in_sizes, int n_in,
                              void* d_out, int out_size, void* d_ws, size_t ws_size,
                              hipStream_t stream) {
    const float* loc      = (const float*)d_in[0];
    const float* deadline = (const float*)d_in[1];
    const float* depot    = (const float*)d_in[2];
    const float* W3d      = (const float*)d_in[3];
    const float* b3d      = (const float*)d_in[4];
    const float* W2d      = (const float*)d_in[5];
    const float* b2d      = (const float*)d_in[6];
    const float* Wnb      = (const float*)d_in[7];
    const float* bnb      = (const float*)d_in[8];
    const float* Wdep     = (const float*)d_in[9];
    const float* bdep     = (const float*)d_in[10];
    float* out = (float*)d_out;

    char* ws = (char*)d_ws;
    unsigned short* G16   = (unsigned short*)(ws + WS_G);
    unsigned short* nbrs  = (unsigned short*)(ws + WS_NBRS);
    unsigned short* ids   = (unsigned short*)(ws + WS_IDS);
    int* starts           = (int*)(ws + WS_STARTS);
    float* partials       = (float*)(ws + WS_PART);
    float2* xys           = (float2*)(ws + WS_XYS);

    k_gridg<<<112, 256, 0, stream>>>(loc, W2d, b2d, Wnb, ids, starts, G16,
                                     xys);
    k_knn<<<1024, 512, 0, stream>>>(xys, ids, starts, nbrs);
    k_gather<<<1024, 256, 0, stream>>>(loc, deadline, nbrs, ids, G16, W3d,
                                       b3d, bnb, out, partials);
    k_fin<<<32, 256, 0, stream>>>(depot, Wdep, bdep, partials, out);
}